// Round 5
// baseline (379.410 us; speedup 1.0000x reference)
//
#include <hip/hip_runtime.h>
#include <stdint.h>

#define TLEN   2048
#define DMODEL 1024
#define DINNER 2048
#define MROWS  8192   // B*T
#define NCH    64
#define CHUNK  32

typedef unsigned short u16;
typedef __bf16 bf16x8 __attribute__((ext_vector_type(8)));
typedef float  f32x4  __attribute__((ext_vector_type(4)));

__device__ __forceinline__ float bf2f(u16 u) {
  union { unsigned int i; float f; } v; v.i = ((unsigned int)u) << 16; return v.f;
}
__device__ __forceinline__ u16 f2bf(float f) {
  union { float f; unsigned int u; } v; v.f = f;
  unsigned int u = v.u;
  return (u16)((u + 0x7fffu + ((u >> 16) & 1u)) >> 16);
}
__device__ __forceinline__ float silu_f(float x) { return x / (1.f + __expf(-x)); }

__device__ __forceinline__ void async16(const u16* g, u16* l) {
  __builtin_amdgcn_global_load_lds(
      (const __attribute__((address_space(1))) void*)(g),
      (__attribute__((address_space(3))) void*)(l),
      16, 0, 0);
}

#define BAR      asm volatile("s_barrier" ::: "memory")
#define WAITV(n) asm volatile("s_waitcnt vmcnt(" #n ")" ::: "memory")
#define PRIO1    __builtin_amdgcn_s_setprio(1)
#define PRIO0    __builtin_amdgcn_s_setprio(0)

// ---------------- fp32 -> bf16 conversion: x, in_proj_w, out_proj_w, xpw -------
__global__ __launch_bounds__(256) void k_convert(const float* __restrict__ x,
    const float* __restrict__ w1, const float* __restrict__ w3,
    const float* __restrict__ xpw,
    u16* __restrict__ xb, u16* __restrict__ w1b, u16* __restrict__ w3b,
    u16* __restrict__ xpwb) {
  int i = blockIdx.x * 256 + threadIdx.x;           // one float4 per thread
  const int nx  = MROWS * DMODEL / 4;               // 2097152
  const int nw1 = 2 * DINNER * DMODEL / 4;          // 1048576
  const int nw3 = DMODEL * DINNER / 4;              //  524288
  const float* src; u16* dst; int j;
  if (i < nx)                  { src = x;   dst = xb;   j = i; }
  else if (i < nx + nw1)       { src = w1;  dst = w1b;  j = i - nx; }
  else if (i < nx + nw1 + nw3) { src = w3;  dst = w3b;  j = i - nx - nw1; }
  else                         { src = xpw; dst = xpwb; j = i - nx - nw1 - nw3; }
  float4 v = ((const float4*)src)[j];
  ushort4 o;
  o.x = f2bf(v.x); o.y = f2bf(v.y); o.z = f2bf(v.z); o.w = f2bf(v.w);
  ((ushort4*)dst)[j] = o;
}

// ================= 256x256 8-phase bf16 GEMM (round-2 schedule, 72 us) =========
__device__ __forceinline__ u16* regp(u16* lds, int s, int mat, int h) {
  return lds + (((s * 2 + mat) * 2 + h) * 8192);
}

__device__ __forceinline__ void read_a(bf16x8 (&dst)[4][2], const u16* reg,
                                       int qa, int fr, int c0, int c1) {
  #pragma unroll
  for (int m = 0; m < 4; m++) {
    const u16* p = reg + (qa * 64 + m * 16 + fr) * 64;
    dst[m][0] = *(const bf16x8*)(p + c0);
    dst[m][1] = *(const bf16x8*)(p + c1);
  }
}
__device__ __forceinline__ void read_b(bf16x8 (&dst)[2][2], const u16* reg,
                                       int rb, int c0, int c1) {
  #pragma unroll
  for (int n = 0; n < 2; n++) {
    const u16* p = reg + (rb + n * 16) * 64;
    dst[n][0] = *(const bf16x8*)(p + c0);
    dst[n][1] = *(const bf16x8*)(p + c1);
  }
}
__device__ __forceinline__ void mfma_quad(f32x4 (&acc)[8][4],
    const bf16x8 (&af)[4][2], const bf16x8 (&bf)[2][2], int qa, int qb) {
  #pragma unroll
  for (int m = 0; m < 4; m++)
    #pragma unroll
    for (int n = 0; n < 2; n++)
      #pragma unroll
      for (int ks = 0; ks < 2; ks++)
        acc[qa * 4 + m][qb * 2 + n] = __builtin_amdgcn_mfma_f32_16x16x32_bf16(
            af[m][ks], bf[n][ks], acc[qa * 4 + m][qb * 2 + n], 0, 0, 0);
}

template<int N, int K, bool OUT_BF16>
__global__ __launch_bounds__(512) void k_gemm8p(const u16* __restrict__ A,
    const u16* __restrict__ Bm, void* __restrict__ C) {
  static_assert(K % 128 == 0, "K must be multiple of 128");
  extern __shared__ u16 lds[];
  const int tid  = threadIdx.x;
  const int lane = tid & 63;
  const int wave = tid >> 6;
  const int wm   = wave >> 2;
  const int wn   = wave & 3;
  const int fr   = lane & 15;
  const int q    = lane >> 4;

  int wg = blockIdx.x, nwg = gridDim.x, swz = wg;
  if ((nwg & 7) == 0) swz = (wg & 7) * (nwg >> 3) + (wg >> 3);
  const int NT_N = N / 256;
  const size_t blockM = (size_t)(swz / NT_N) * 256;
  const size_t blockN = (size_t)(swz % NT_N) * 256;

  const int rsub   = tid >> 3;
  const int srcCol = 8 * ((tid & 7) ^ (rsub & 7));
  const u16* gA = A  + (blockM + rsub) * (size_t)K + srcCol;
  const u16* gB = Bm + (blockN + rsub) * (size_t)K + srcCol;

#define STAGE(sl, mat, h, kt) do {                                           \
    const u16* _g = ((mat) ? gB : gA) + (size_t)(h) * (128 * (size_t)K)      \
                    + (size_t)(kt) * 64;                                     \
    u16* _l = regp(lds, (sl), (mat), (h)) + tid * 8;                         \
    async16(_g, _l);                                                         \
    async16(_g + (size_t)64 * K, _l + 4096);                                 \
  } while (0)

  const int c0 = (((q * 16)      ^ ((fr & 7) << 4)) >> 1);
  const int c1 = (((64 + q * 16) ^ ((fr & 7) << 4)) >> 1);
  const int rb = (wn & 1) * 64 + fr;

  f32x4 acc[8][4] = {};
  bf16x8 a0[4][2], a1[4][2], bl[2][2], bh[2][2];

  const int NT = K / 64;
  const int NITER = K / 128;

  STAGE(0, 0, 0, 0); STAGE(0, 0, 1, 0); STAGE(0, 1, 0, 0); STAGE(0, 1, 1, 0);
  STAGE(1, 1, 0, 1); STAGE(1, 1, 1, 1); STAGE(1, 0, 0, 1);
  WAITV(6);
  BAR;

  for (int it = 0; it < NITER; ++it) {
    const int t2 = 2 * it + 2, t3 = 2 * it + 3;
    const bool pf = (t2 < NT);
    // ---- P1
    read_a(a0, regp(lds, 0, 0, wm), 0, fr, c0, c1);
    read_b(bl, regp(lds, 0, 1, wn >> 1), rb, c0, c1);
    STAGE(1, 0, 1, 2 * it + 1);
    BAR;
    PRIO1; mfma_quad(acc, a0, bl, 0, 0); PRIO0;
    BAR;
    // ---- P2
    read_b(bh, regp(lds, 0, 1, wn >> 1), rb + 32, c0, c1);
    if (pf) STAGE(0, 1, 0, t2);
    BAR;
    PRIO1; mfma_quad(acc, a0, bh, 0, 1); PRIO0;
    BAR;
    // ---- P3
    read_a(a1, regp(lds, 0, 0, wm), 1, fr, c0, c1);
    if (pf) STAGE(0, 1, 1, t2);
    BAR;
    PRIO1; mfma_quad(acc, a1, bl, 1, 0); PRIO0;
    BAR;
    // ---- P4
    if (pf) STAGE(0, 0, 0, t2);
    BAR;
    PRIO1; mfma_quad(acc, a1, bh, 1, 1); PRIO0;
    if (pf) { WAITV(6); } else { WAITV(0); }
    BAR;
    // ---- P5
    read_a(a0, regp(lds, 1, 0, wm), 0, fr, c0, c1);
    read_b(bl, regp(lds, 1, 1, wn >> 1), rb, c0, c1);
    if (pf) STAGE(0, 0, 1, t2);
    BAR;
    PRIO1; mfma_quad(acc, a0, bl, 0, 0); PRIO0;
    BAR;
    // ---- P6
    read_b(bh, regp(lds, 1, 1, wn >> 1), rb + 32, c0, c1);
    if (pf) STAGE(1, 1, 0, t3);
    BAR;
    PRIO1; mfma_quad(acc, a0, bh, 0, 1); PRIO0;
    BAR;
    // ---- P7
    read_a(a1, regp(lds, 1, 0, wm), 1, fr, c0, c1);
    if (pf) STAGE(1, 1, 1, t3);
    BAR;
    PRIO1; mfma_quad(acc, a1, bl, 1, 0); PRIO0;
    BAR;
    // ---- P8
    if (pf) STAGE(1, 0, 0, t3);
    BAR;
    PRIO1; mfma_quad(acc, a1, bh, 1, 1); PRIO0;
    if (pf) { WAITV(6); BAR; } else { BAR; }
  }
#undef STAGE

  {
    const size_t r0  = blockM + (size_t)wm * 128;
    const size_t cc0 = blockN + (size_t)wn * 64;
    #pragma unroll
    for (int m = 0; m < 8; m++)
      #pragma unroll
      for (int n = 0; n < 4; n++)
        #pragma unroll
        for (int r = 0; r < 4; r++) {
          size_t row = r0 + m * 16 + q * 4 + r;
          size_t col = cc0 + n * 16 + fr;
          float v = acc[m][n][r];
          if (OUT_BF16) ((u16*)C)[row * N + col] = f2bf(v);
          else          ((float*)C)[row * N + col] = v;
        }
  }
}

// ---------------- gemm2: 128M x 64N tile, 1024 blocks = 4/CU (out_proj) --------
// C[M,1024] = A[M,2048] * B[1024,2048]^T, fp32 out. 4 waves: wave owns 64x32.
template<int N, int K>
__global__ __launch_bounds__(256) void k_gemm2(const u16* __restrict__ A,
    const u16* __restrict__ B, float* __restrict__ C) {
  __shared__ u16 sA[2][128 * 32];       // 16 KB
  __shared__ u16 sB[2][64 * 32];        //  8 KB
  const int tid  = threadIdx.x;
  const int lane = tid & 63;
  const int wave = tid >> 6;            // 0..3
  const int wm   = (wave >> 1) * 64;
  const int wn   = (wave & 1) * 32;
  const int fr   = lane & 15;
  const int q    = lane >> 4;
  const size_t blockM = (size_t)blockIdx.y * 128;
  const size_t blockN = (size_t)blockIdx.x * 64;

  const int srow = lane >> 2;           // 0..15
  const int scol = (lane & 3) * 8;
  const u16* gA = A + (blockM + (size_t)wave * 32 + srow) * (size_t)K + scol;
  const u16* gB = B + (blockN + (size_t)wave * 16 + srow) * (size_t)K + scol;
  u16* lA0 = sA[0] + wave * 1024;
  u16* lA1 = sA[1] + wave * 1024;
  u16* lB0 = sB[0] + wave * 512;
  u16* lB1 = sB[1] + wave * 512;

  f32x4 acc[4][2] = {};

  for (int kt = 0; kt < K; kt += 64) {
    async16(gA + kt,                        lA0);
    async16(gA + 16 * (size_t)K + kt,       lA0 + 512);
    async16(gA + kt + 32,                   lA1);
    async16(gA + 16 * (size_t)K + kt + 32,  lA1 + 512);
    async16(gB + kt,                        lB0);
    async16(gB + kt + 32,                   lB1);
    __syncthreads();

    #pragma unroll
    for (int h = 0; h < 2; h++) {
      bf16x8 af[4], bfr[2];
      #pragma unroll
      for (int tm = 0; tm < 4; tm++)
        af[tm] = *(const bf16x8*)(sA[h] + (wm + tm * 16 + fr) * 32 + q * 8);
      #pragma unroll
      for (int tn = 0; tn < 2; tn++)
        bfr[tn] = *(const bf16x8*)(sB[h] + (wn + tn * 16 + fr) * 32 + q * 8);
      #pragma unroll
      for (int tm = 0; tm < 4; tm++)
        #pragma unroll
        for (int tn = 0; tn < 2; tn++)
          acc[tm][tn] = __builtin_amdgcn_mfma_f32_16x16x32_bf16(
              af[tm], bfr[tn], acc[tm][tn], 0, 0, 0);
    }
    __syncthreads();
  }

  #pragma unroll
  for (int tm = 0; tm < 4; tm++)
    #pragma unroll
    for (int tn = 0; tn < 2; tn++)
      #pragma unroll
      for (int r = 0; r < 4; r++) {
        size_t row = blockM + wm + tm * 16 + q * 4 + r;
        size_t col = blockN + wn + tn * 16 + fr;
        C[row * N + col] = acc[tm][tn][r];
      }
}

// ---------------- depthwise causal conv + SiLU: 8 d x 8 t per thread -----------
__global__ __launch_bounds__(256) void k_conv(const u16* __restrict__ xz,
    const float* __restrict__ cw, const float* __restrict__ cb,
    u16* __restrict__ xc) {
  const int tb = blockIdx.x & 255;
  const int b  = blockIdx.x >> 8;
  const int d0 = threadIdx.x * 8;

  float wgt[8][4], bias[8];
  #pragma unroll
  for (int j = 0; j < 8; j++) {
    float4 wv = ((const float4*)cw)[d0 + j];
    wgt[j][0] = wv.x; wgt[j][1] = wv.y; wgt[j][2] = wv.z; wgt[j][3] = wv.w;
    bias[j] = cb[d0 + j];
  }

  const int t0 = tb * 8;
  const u16* base = xz + ((size_t)(b * TLEN + t0)) * 4096 + d0;
  float win[3][8];
  #pragma unroll
  for (int k = 0; k < 3; k++) {
    const int t = t0 - 3 + k;
    if (t >= 0) {
      bf16x8 v = *(const bf16x8*)(base + (ptrdiff_t)(k - 3) * 4096);
      #pragma unroll
      for (int j = 0; j < 8; j++) win[k][j] = bf2f(((u16*)&v)[j]);
    } else {
      #pragma unroll
      for (int j = 0; j < 8; j++) win[k][j] = 0.f;
    }
  }

  u16* outp = xc + ((size_t)(b * TLEN + t0)) * DINNER + d0;
  #pragma unroll
  for (int i = 0; i < 8; i++) {
    bf16x8 v = *(const bf16x8*)(base + (ptrdiff_t)i * 4096);
    float cur[8];
    #pragma unroll
    for (int j = 0; j < 8; j++) cur[j] = bf2f(((u16*)&v)[j]);
    union { u16 a[8]; int4 v4; } o;
    #pragma unroll
    for (int j = 0; j < 8; j++) {
      float acc = bias[j] + wgt[j][0] * win[0][j] + wgt[j][1] * win[1][j]
                + wgt[j][2] * win[2][j] + wgt[j][3] * cur[j];
      o.a[j] = f2bf(silu_f(acc));
    }
    *(int4*)(outp + (size_t)i * DINNER) = o.v4;
    #pragma unroll
    for (int j = 0; j < 8; j++) { win[0][j] = win[1][j]; win[1][j] = win[2][j]; win[2][j] = cur[j]; }
  }
}

// ---------------- fused bssm (MFMA) + alpha + chunk-scan, one 32-row chunk -----
// grid = 256 blocks (= b*64+c chunks), 256 threads.
__global__ __launch_bounds__(256) void k_fused(const u16* __restrict__ xc,
    const u16* __restrict__ xpwb, const float* __restrict__ dtw,
    const float* __restrict__ dtb, float* __restrict__ alpha,
    float* __restrict__ Pprod, float* __restrict__ carry) {
  const int tid  = threadIdx.x;
  const int lane = tid & 63;
  const int wave = tid >> 6;
  const int fr   = lane & 15;
  const int q    = lane >> 4;
  const size_t row0 = (size_t)blockIdx.x * 32;
  const int k0 = wave * 512;

  // phase 1: B_ssm[32][16] via MFMA (K split across 4 waves) -> sBs
  f32x4 acc[2] = {};
  #pragma unroll
  for (int kk = 0; kk < 512; kk += 32) {
    const int kb = k0 + kk + q * 8;
    bf16x8 bfrag = *(const bf16x8*)(xpwb + (size_t)fr * DINNER + kb);
    #pragma unroll
    for (int tm = 0; tm < 2; tm++) {
      bf16x8 afrag = *(const bf16x8*)(xc + (row0 + tm * 16 + fr) * (size_t)DINNER + kb);
      acc[tm] = __builtin_amdgcn_mfma_f32_16x16x32_bf16(afrag, bfrag, acc[tm], 0, 0, 0);
    }
  }
  __shared__ float red[4][32][16];      // 8 KB
  #pragma unroll
  for (int tm = 0; tm < 2; tm++)
    #pragma unroll
    for (int r = 0; r < 4; r++)
      red[wave][tm * 16 + q * 4 + r][fr] = acc[tm][r];
  __syncthreads();
  __shared__ float sBs[32][16];
  for (int i = tid; i < 512; i += 256) {
    int r = i >> 4, n = i & 15;
    sBs[r][n] = red[0][r][n] + red[1][r][n] + red[2][r][n] + red[3][r][n];
  }
  __syncthreads();

  // phase 2: alpha[r] = sigmoid(mean_d softplus(sBs[r].dtw[d] + dtb[d]))
  // 8 threads per row; thread covers d = ds + 8k (coalesced across the group).
  __shared__ float sA2[32];
  {
    const int r  = tid >> 3;
    const int ds = tid & 7;
    float4 b0 = *(const float4*)&sBs[r][0];
    float4 b1 = *(const float4*)&sBs[r][4];
    float4 b2 = *(const float4*)&sBs[r][8];
    float4 b3 = *(const float4*)&sBs[r][12];
    float s = 0.f;
    for (int k = 0; k < 256; k++) {
      const int d = ds + k * 8;
      const float4* wp = (const float4*)(dtw + (size_t)d * 16);
      float4 w0 = wp[0], w1 = wp[1], w2 = wp[2], w3 = wp[3];
      float dot = dtb[d]
        + b0.x * w0.x + b0.y * w0.y + b0.z * w0.z + b0.w * w0.w
        + b1.x * w1.x + b1.y * w1.y + b1.z * w1.z + b1.w * w1.w
        + b2.x * w2.x + b2.y * w2.y + b2.z * w2.z + b2.w * w2.w
        + b3.x * w3.x + b3.y * w3.y + b3.z * w3.z + b3.w * w3.w;
      s += (dot > 15.f) ? dot : __logf(1.f + __expf(dot));
    }
    s += __shfl_xor(s, 1); s += __shfl_xor(s, 2); s += __shfl_xor(s, 4);
    if (ds == 0) sA2[r] = s;
  }
  __syncthreads();
  if (tid < 32) {
    float mean = sA2[tid] * (1.f / DINNER);
    float a = 1.f / (1.f + __expf(-mean));
    sA2[tid] = a;
    alpha[row0 + tid] = a;
  }
  __syncthreads();
  if (tid == 0) {
    float p = 1.f;
    #pragma unroll
    for (int i = 0; i < 32; i++) p *= sA2[i];
    Pprod[blockIdx.x] = p;
  }

  // phase 3: local scan of the 32 rows from h=0 -> carry
  {
    const int d0 = tid * 8;
    float h[8];
    #pragma unroll
    for (int j = 0; j < 8; j++) h[j] = 0.f;
    const u16* xp = xc + row0 * DINNER + d0;
    for (int i = 0; i < 32; i++) {
      bf16x8 v = *(const bf16x8*)(xp + (size_t)i * DINNER);
      float a = sA2[i];
      #pragma unroll
      for (int j = 0; j < 8; j++)
        h[j] = a * h[j] + (1.f - a) * bf2f(((u16*)&v)[j]);
    }
    float* cp = carry + (size_t)blockIdx.x * DINNER + d0;
    #pragma unroll
    for (int j = 0; j < 8; j++) cp[j] = h[j];
  }
}

// ---------------- scan pass 2: carry combine, cv preloaded in registers --------
__global__ __launch_bounds__(256) void k_scan2(float* __restrict__ carry,
    const float* __restrict__ Pprod) {
  int i = blockIdx.x * 256 + threadIdx.x;   // 0..8191 = (b, d)
  int b = i >> 11;
  int d = i & (DINNER - 1);
  __shared__ float sP[NCH];
  if (threadIdx.x < NCH) sP[threadIdx.x] = Pprod[b * NCH + threadIdx.x];
  __syncthreads();
  float* base = carry + (size_t)b * NCH * DINNER + d;
  float cv[NCH];
  #pragma unroll
  for (int c = 0; c < NCH; c++) cv[c] = base[(size_t)c * DINNER];
  float h = 0.f;
  #pragma unroll
  for (int c = 0; c < NCH; c++) {
    base[(size_t)c * DINNER] = h;       // chunk-entry state Hs
    h = sP[c] * h + cv[c];
  }
}

// ---------------- scan pass 3: re-scan + fused y = (h*D + xc)*silu(z) ----------
// grid (b, c, dhalf) = 512 blocks; 256 thr, thread = 4 d's (8B loads).
__global__ __launch_bounds__(256) void k_scan3(const u16* __restrict__ xc,
    const u16* __restrict__ xz, const float* __restrict__ alpha,
    const float* __restrict__ Hs, const float* __restrict__ Dp,
    u16* __restrict__ yg) {
  const int half = blockIdx.x & 1;
  const int c = (blockIdx.x >> 1) & 63;
  const int b = blockIdx.x >> 7;
  const int d0 = half * 1024 + threadIdx.x * 4;
  __shared__ float sa[CHUNK];
  if (threadIdx.x < CHUNK) sa[threadIdx.x] = alpha[b * TLEN + c * CHUNK + threadIdx.x];
  __syncthreads();
  float h[4], Dv[4];
  { const float* hp = Hs + ((size_t)(b * NCH + c)) * DINNER + d0;
    #pragma unroll
    for (int j = 0; j < 4; j++) { h[j] = hp[j]; Dv[j] = Dp[d0 + j]; } }
  const size_t row0 = (size_t)(b * TLEN + c * CHUNK);
  #pragma unroll 2
  for (int i = 0; i < CHUNK; i++) {
    const size_t row = row0 + i;
    ushort4 xv4 = *(const ushort4*)(xc + row * DINNER + d0);
    ushort4 zv4 = *(const ushort4*)(xz + row * 4096 + DINNER + d0);
    const float a = sa[i];
    union { u16 o[4]; uint2 v2; } out;
    const u16* xv = (const u16*)&xv4;
    const u16* zv = (const u16*)&zv4;
    #pragma unroll
    for (int j = 0; j < 4; j++) {
      float x = bf2f(xv[j]);
      float z = bf2f(zv[j]);
      h[j] = a * h[j] + (1.f - a) * x;
      float y = h[j] * Dv[j] + x;
      out.o[j] = f2bf(y * silu_f(z));
    }
    *(uint2*)(yg + row * DINNER + d0) = out.v2;
  }
}

// ---------------- launch --------------------------------------------------------
extern "C" void kernel_launch(void* const* d_in, const int* in_sizes, int n_in,
                              void* d_out, int out_size, void* d_ws, size_t ws_size,
                              hipStream_t stream) {
  const float* x   = (const float*)d_in[0];
  const float* w1  = (const float*)d_in[1];
  const float* cw  = (const float*)d_in[2];
  const float* cb  = (const float*)d_in[3];
  const float* xpw = (const float*)d_in[4];
  const float* dtw = (const float*)d_in[5];
  const float* dtb = (const float*)d_in[6];
  const float* Dp  = (const float*)d_in[7];
  const float* w3  = (const float*)d_in[8];
  float* out = (float*)d_out;
  char* ws = (char*)d_ws;

  u16*   xb    = (u16*)(ws + 0);            // 16.78 MB (dead after gemm1)
  u16*   w1b   = (u16*)(ws + 16777216);     //  8.39 MB
  u16*   w3b   = (u16*)(ws + 25165824);     //  4.19 MB
  u16*   xz    = (u16*)(ws + 29360128);     // 67.11 MB  [8192][4096] bf16
  u16*   xc    = (u16*)(ws + 96468992);     // 33.55 MB  [8192][2048] bf16
  u16*   yg    = (u16*)(ws + 130023424);    // 33.55 MB  [8192][2048] bf16
  float* Pprod = (float*)(ws + 163577856);  // 1 KB      [256]
  float* alpha = (float*)(ws + 164102144);  // 32 KB     [8192]
  float* carry = (float*)(ws + 0);          // 2 MB [256][2048] — reuses dead xb
  u16*   xpwb  = (u16*)(ws + 164659456);    // 64 KB     [16][2048] bf16

  k_convert<<<14368, 256, 0, stream>>>(x, w1, w3, xpw, xb, w1b, w3b, xpwb);
  k_gemm8p<4096, 1024, true><<<512, 512, 131072, stream>>>(xb, w1b, xz);
  k_conv   <<<1024, 256, 0, stream>>>(xz, cw, cb, xc);
  k_fused  <<<256, 256, 0, stream>>>(xc, xpwb, dtw, dtb, alpha, Pprod, carry);
  k_scan2  <<<32, 256, 0, stream>>>(carry, Pprod);
  k_scan3  <<<512, 256, 0, stream>>>(xc, xz, alpha, carry, Dp, yg);
  k_gemm2<1024, 2048><<<dim3(16, 64), 256, 0, stream>>>(yg, w3b, out);
}

// Round 6
// 339.055 us; speedup vs baseline: 1.1190x; 1.1190x over previous
//
#include <hip/hip_runtime.h>
#include <stdint.h>

#define TLEN   2048
#define DMODEL 1024
#define DINNER 2048
#define MROWS  8192   // B*T
#define NCH    64
#define CHUNK  32

typedef unsigned short u16;
typedef __bf16 bf16x8 __attribute__((ext_vector_type(8)));
typedef float  f32x4  __attribute__((ext_vector_type(4)));

__device__ __forceinline__ float bf2f(u16 u) {
  union { unsigned int i; float f; } v; v.i = ((unsigned int)u) << 16; return v.f;
}
__device__ __forceinline__ u16 f2bf(float f) {
  union { float f; unsigned int u; } v; v.f = f;
  unsigned int u = v.u;
  return (u16)((u + 0x7fffu + ((u >> 16) & 1u)) >> 16);
}
__device__ __forceinline__ float silu_f(float x) { return x / (1.f + __expf(-x)); }

__device__ __forceinline__ void async16(const u16* g, u16* l) {
  __builtin_amdgcn_global_load_lds(
      (const __attribute__((address_space(1))) void*)(g),
      (__attribute__((address_space(3))) void*)(l),
      16, 0, 0);
}

#define BAR      asm volatile("s_barrier" ::: "memory")
#define WAITV(n) asm volatile("s_waitcnt vmcnt(" #n ")" ::: "memory")
#define PRIO1    __builtin_amdgcn_s_setprio(1)
#define PRIO0    __builtin_amdgcn_s_setprio(0)

// ---------------- fp32 -> bf16 conversion: x, in_proj_w, out_proj_w, xpw -------
__global__ __launch_bounds__(256) void k_convert(const float* __restrict__ x,
    const float* __restrict__ w1, const float* __restrict__ w3,
    const float* __restrict__ xpw,
    u16* __restrict__ xb, u16* __restrict__ w1b, u16* __restrict__ w3b,
    u16* __restrict__ xpwb) {
  int i = blockIdx.x * 256 + threadIdx.x;           // one float4 per thread
  const int nx  = MROWS * DMODEL / 4;               // 2097152
  const int nw1 = 2 * DINNER * DMODEL / 4;          // 1048576
  const int nw3 = DMODEL * DINNER / 4;              //  524288
  const float* src; u16* dst; int j;
  if (i < nx)                  { src = x;   dst = xb;   j = i; }
  else if (i < nx + nw1)       { src = w1;  dst = w1b;  j = i - nx; }
  else if (i < nx + nw1 + nw3) { src = w3;  dst = w3b;  j = i - nx - nw1; }
  else                         { src = xpw; dst = xpwb; j = i - nx - nw1 - nw3; }
  float4 v = ((const float4*)src)[j];
  ushort4 o;
  o.x = f2bf(v.x); o.y = f2bf(v.y); o.z = f2bf(v.z); o.w = f2bf(v.w);
  ((ushort4*)dst)[j] = o;
}

// ================= 256x256 8-phase bf16 GEMM (round-2 schedule, 72 us) =========
__device__ __forceinline__ u16* regp(u16* lds, int s, int mat, int h) {
  return lds + (((s * 2 + mat) * 2 + h) * 8192);
}

__device__ __forceinline__ void read_a(bf16x8 (&dst)[4][2], const u16* reg,
                                       int qa, int fr, int c0, int c1) {
  #pragma unroll
  for (int m = 0; m < 4; m++) {
    const u16* p = reg + (qa * 64 + m * 16 + fr) * 64;
    dst[m][0] = *(const bf16x8*)(p + c0);
    dst[m][1] = *(const bf16x8*)(p + c1);
  }
}
__device__ __forceinline__ void read_b(bf16x8 (&dst)[2][2], const u16* reg,
                                       int rb, int c0, int c1) {
  #pragma unroll
  for (int n = 0; n < 2; n++) {
    const u16* p = reg + (rb + n * 16) * 64;
    dst[n][0] = *(const bf16x8*)(p + c0);
    dst[n][1] = *(const bf16x8*)(p + c1);
  }
}
__device__ __forceinline__ void mfma_quad(f32x4 (&acc)[8][4],
    const bf16x8 (&af)[4][2], const bf16x8 (&bf)[2][2], int qa, int qb) {
  #pragma unroll
  for (int m = 0; m < 4; m++)
    #pragma unroll
    for (int n = 0; n < 2; n++)
      #pragma unroll
      for (int ks = 0; ks < 2; ks++)
        acc[qa * 4 + m][qb * 2 + n] = __builtin_amdgcn_mfma_f32_16x16x32_bf16(
            af[m][ks], bf[n][ks], acc[qa * 4 + m][qb * 2 + n], 0, 0, 0);
}

template<int N, int K, bool OUT_BF16>
__global__ __launch_bounds__(512) void k_gemm8p(const u16* __restrict__ A,
    const u16* __restrict__ Bm, void* __restrict__ C) {
  static_assert(K % 128 == 0, "K must be multiple of 128");
  extern __shared__ u16 lds[];
  const int tid  = threadIdx.x;
  const int lane = tid & 63;
  const int wave = tid >> 6;
  const int wm   = wave >> 2;
  const int wn   = wave & 3;
  const int fr   = lane & 15;
  const int q    = lane >> 4;

  int wg = blockIdx.x, nwg = gridDim.x, swz = wg;
  if ((nwg & 7) == 0) swz = (wg & 7) * (nwg >> 3) + (wg >> 3);
  const int NT_N = N / 256;
  const size_t blockM = (size_t)(swz / NT_N) * 256;
  const size_t blockN = (size_t)(swz % NT_N) * 256;

  const int rsub   = tid >> 3;
  const int srcCol = 8 * ((tid & 7) ^ (rsub & 7));
  const u16* gA = A  + (blockM + rsub) * (size_t)K + srcCol;
  const u16* gB = Bm + (blockN + rsub) * (size_t)K + srcCol;

#define STAGE(sl, mat, h, kt) do {                                           \
    const u16* _g = ((mat) ? gB : gA) + (size_t)(h) * (128 * (size_t)K)      \
                    + (size_t)(kt) * 64;                                     \
    u16* _l = regp(lds, (sl), (mat), (h)) + tid * 8;                         \
    async16(_g, _l);                                                         \
    async16(_g + (size_t)64 * K, _l + 4096);                                 \
  } while (0)

  const int c0 = (((q * 16)      ^ ((fr & 7) << 4)) >> 1);
  const int c1 = (((64 + q * 16) ^ ((fr & 7) << 4)) >> 1);
  const int rb = (wn & 1) * 64 + fr;

  f32x4 acc[8][4] = {};
  bf16x8 a0[4][2], a1[4][2], bl[2][2], bh[2][2];

  const int NT = K / 64;
  const int NITER = K / 128;

  STAGE(0, 0, 0, 0); STAGE(0, 0, 1, 0); STAGE(0, 1, 0, 0); STAGE(0, 1, 1, 0);
  STAGE(1, 1, 0, 1); STAGE(1, 1, 1, 1); STAGE(1, 0, 0, 1);
  WAITV(6);
  BAR;

  for (int it = 0; it < NITER; ++it) {
    const int t2 = 2 * it + 2, t3 = 2 * it + 3;
    const bool pf = (t2 < NT);
    // ---- P1
    read_a(a0, regp(lds, 0, 0, wm), 0, fr, c0, c1);
    read_b(bl, regp(lds, 0, 1, wn >> 1), rb, c0, c1);
    STAGE(1, 0, 1, 2 * it + 1);
    BAR;
    PRIO1; mfma_quad(acc, a0, bl, 0, 0); PRIO0;
    BAR;
    // ---- P2
    read_b(bh, regp(lds, 0, 1, wn >> 1), rb + 32, c0, c1);
    if (pf) STAGE(0, 1, 0, t2);
    BAR;
    PRIO1; mfma_quad(acc, a0, bh, 0, 1); PRIO0;
    BAR;
    // ---- P3
    read_a(a1, regp(lds, 0, 0, wm), 1, fr, c0, c1);
    if (pf) STAGE(0, 1, 1, t2);
    BAR;
    PRIO1; mfma_quad(acc, a1, bl, 1, 0); PRIO0;
    BAR;
    // ---- P4
    if (pf) STAGE(0, 0, 0, t2);
    BAR;
    PRIO1; mfma_quad(acc, a1, bh, 1, 1); PRIO0;
    if (pf) { WAITV(6); } else { WAITV(0); }
    BAR;
    // ---- P5
    read_a(a0, regp(lds, 1, 0, wm), 0, fr, c0, c1);
    read_b(bl, regp(lds, 1, 1, wn >> 1), rb, c0, c1);
    if (pf) STAGE(0, 0, 1, t2);
    BAR;
    PRIO1; mfma_quad(acc, a0, bl, 0, 0); PRIO0;
    BAR;
    // ---- P6
    read_b(bh, regp(lds, 1, 1, wn >> 1), rb + 32, c0, c1);
    if (pf) STAGE(1, 1, 0, t3);
    BAR;
    PRIO1; mfma_quad(acc, a0, bh, 0, 1); PRIO0;
    BAR;
    // ---- P7
    read_a(a1, regp(lds, 1, 0, wm), 1, fr, c0, c1);
    if (pf) STAGE(1, 1, 1, t3);
    BAR;
    PRIO1; mfma_quad(acc, a1, bl, 1, 0); PRIO0;
    BAR;
    // ---- P8
    if (pf) STAGE(1, 0, 0, t3);
    BAR;
    PRIO1; mfma_quad(acc, a1, bh, 1, 1); PRIO0;
    if (pf) { WAITV(6); BAR; } else { BAR; }
  }
#undef STAGE

  {
    const size_t r0  = blockM + (size_t)wm * 128;
    const size_t cc0 = blockN + (size_t)wn * 64;
    #pragma unroll
    for (int m = 0; m < 8; m++)
      #pragma unroll
      for (int n = 0; n < 4; n++)
        #pragma unroll
        for (int r = 0; r < 4; r++) {
          size_t row = r0 + m * 16 + q * 4 + r;
          size_t col = cc0 + n * 16 + fr;
          float v = acc[m][n][r];
          if (OUT_BF16) ((u16*)C)[row * N + col] = f2bf(v);
          else          ((float*)C)[row * N + col] = v;
        }
  }
}

// ---------------- gemm2: 128M x 64N tile, 1024 blocks = 4/CU (out_proj) --------
// C[M,1024] = A[M,2048] * B[1024,2048]^T, fp32 out. 4 waves: wave owns 64x32.
template<int N, int K>
__global__ __launch_bounds__(256) void k_gemm2(const u16* __restrict__ A,
    const u16* __restrict__ B, float* __restrict__ C) {
  __shared__ u16 sA[2][128 * 32];       // 16 KB
  __shared__ u16 sB[2][64 * 32];        //  8 KB
  const int tid  = threadIdx.x;
  const int lane = tid & 63;
  const int wave = tid >> 6;            // 0..3
  const int wm   = (wave >> 1) * 64;
  const int wn   = (wave & 1) * 32;
  const int fr   = lane & 15;
  const int q    = lane >> 4;
  const size_t blockM = (size_t)blockIdx.y * 128;
  const size_t blockN = (size_t)blockIdx.x * 64;

  const int srow = lane >> 2;           // 0..15
  const int scol = (lane & 3) * 8;
  const u16* gA = A + (blockM + (size_t)wave * 32 + srow) * (size_t)K + scol;
  const u16* gB = B + (blockN + (size_t)wave * 16 + srow) * (size_t)K + scol;
  u16* lA0 = sA[0] + wave * 1024;
  u16* lA1 = sA[1] + wave * 1024;
  u16* lB0 = sB[0] + wave * 512;
  u16* lB1 = sB[1] + wave * 512;

  f32x4 acc[4][2] = {};

  for (int kt = 0; kt < K; kt += 64) {
    async16(gA + kt,                        lA0);
    async16(gA + 16 * (size_t)K + kt,       lA0 + 512);
    async16(gA + kt + 32,                   lA1);
    async16(gA + 16 * (size_t)K + kt + 32,  lA1 + 512);
    async16(gB + kt,                        lB0);
    async16(gB + kt + 32,                   lB1);
    __syncthreads();

    #pragma unroll
    for (int h = 0; h < 2; h++) {
      bf16x8 af[4], bfr[2];
      #pragma unroll
      for (int tm = 0; tm < 4; tm++)
        af[tm] = *(const bf16x8*)(sA[h] + (wm + tm * 16 + fr) * 32 + q * 8);
      #pragma unroll
      for (int tn = 0; tn < 2; tn++)
        bfr[tn] = *(const bf16x8*)(sB[h] + (wn + tn * 16 + fr) * 32 + q * 8);
      #pragma unroll
      for (int tm = 0; tm < 4; tm++)
        #pragma unroll
        for (int tn = 0; tn < 2; tn++)
          acc[tm][tn] = __builtin_amdgcn_mfma_f32_16x16x32_bf16(
              af[tm], bfr[tn], acc[tm][tn], 0, 0, 0);
    }
    __syncthreads();
  }

  #pragma unroll
  for (int tm = 0; tm < 4; tm++)
    #pragma unroll
    for (int tn = 0; tn < 2; tn++)
      #pragma unroll
      for (int r = 0; r < 4; r++) {
        size_t row = blockM + wm + tm * 16 + q * 4 + r;
        size_t col = blockN + wn + tn * 16 + fr;
        C[row * N + col] = acc[tm][tn][r];
      }
}

// ---------------- depthwise causal conv + SiLU: 8 d x 8 t per thread -----------
__global__ __launch_bounds__(256) void k_conv(const u16* __restrict__ xz,
    const float* __restrict__ cw, const float* __restrict__ cb,
    u16* __restrict__ xc) {
  const int tb = blockIdx.x & 255;
  const int b  = blockIdx.x >> 8;
  const int d0 = threadIdx.x * 8;

  float wgt[8][4], bias[8];
  #pragma unroll
  for (int j = 0; j < 8; j++) {
    float4 wv = ((const float4*)cw)[d0 + j];
    wgt[j][0] = wv.x; wgt[j][1] = wv.y; wgt[j][2] = wv.z; wgt[j][3] = wv.w;
    bias[j] = cb[d0 + j];
  }

  const int t0 = tb * 8;
  const u16* base = xz + ((size_t)(b * TLEN + t0)) * 4096 + d0;
  float win[3][8];
  #pragma unroll
  for (int k = 0; k < 3; k++) {
    const int t = t0 - 3 + k;
    if (t >= 0) {
      bf16x8 v = *(const bf16x8*)(base + (ptrdiff_t)(k - 3) * 4096);
      #pragma unroll
      for (int j = 0; j < 8; j++) win[k][j] = bf2f(((u16*)&v)[j]);
    } else {
      #pragma unroll
      for (int j = 0; j < 8; j++) win[k][j] = 0.f;
    }
  }

  u16* outp = xc + ((size_t)(b * TLEN + t0)) * DINNER + d0;
  #pragma unroll
  for (int i = 0; i < 8; i++) {
    bf16x8 v = *(const bf16x8*)(base + (ptrdiff_t)i * 4096);
    float cur[8];
    #pragma unroll
    for (int j = 0; j < 8; j++) cur[j] = bf2f(((u16*)&v)[j]);
    union { u16 a[8]; int4 v4; } o;
    #pragma unroll
    for (int j = 0; j < 8; j++) {
      float acc = bias[j] + wgt[j][0] * win[0][j] + wgt[j][1] * win[1][j]
                + wgt[j][2] * win[2][j] + wgt[j][3] * cur[j];
      o.a[j] = f2bf(silu_f(acc));
    }
    *(int4*)(outp + (size_t)i * DINNER) = o.v4;
    #pragma unroll
    for (int j = 0; j < 8; j++) { win[0][j] = win[1][j]; win[1][j] = win[2][j]; win[2][j] = cur[j]; }
  }
}

// ---------------- B_ssm = xc[8192x2048] . xpwb[16x2048]^T  (skinny MFMA) -------
__global__ __launch_bounds__(256) void k_bssm(const u16* __restrict__ xc,
    const u16* __restrict__ xpwb, float* __restrict__ bssm) {
  const int tid  = threadIdx.x;
  const int lane = tid & 63;
  const int wave = tid >> 6;            // splits K
  const int fr   = lane & 15;
  const int q    = lane >> 4;
  const size_t row0 = (size_t)blockIdx.x * 32;
  const int k0 = wave * 512;

  f32x4 acc[2] = {};
  #pragma unroll
  for (int kk = 0; kk < 512; kk += 32) {
    const int kb = k0 + kk + q * 8;
    bf16x8 bfrag = *(const bf16x8*)(xpwb + (size_t)fr * DINNER + kb);
    #pragma unroll
    for (int tm = 0; tm < 2; tm++) {
      bf16x8 afrag = *(const bf16x8*)(xc + (row0 + tm * 16 + fr) * (size_t)DINNER + kb);
      acc[tm] = __builtin_amdgcn_mfma_f32_16x16x32_bf16(afrag, bfrag, acc[tm], 0, 0, 0);
    }
  }

  __shared__ float red[4][32][16];      // 8 KB
  #pragma unroll
  for (int tm = 0; tm < 2; tm++)
    #pragma unroll
    for (int r = 0; r < 4; r++)
      red[wave][tm * 16 + q * 4 + r][fr] = acc[tm][r];
  __syncthreads();
  #pragma unroll
  for (int i = tid; i < 512; i += 256) {
    int r = i >> 4, n = i & 15;
    bssm[(row0 + r) * 16 + n] =
        red[0][r][n] + red[1][r][n] + red[2][r][n] + red[3][r][n];
  }
}

// ---------------- alpha: 16 rows/block, 2 d-cols/thread/pass, 4 passes ---------
__global__ __launch_bounds__(256) void k_alpha(const float* __restrict__ bssm,
    const float* __restrict__ dtw, const float* __restrict__ dtb,
    float* __restrict__ alpha) {
  const int tid = threadIdx.x;
  const size_t row0 = (size_t)blockIdx.x * 16;
  __shared__ float4 sB[16][4];
  { int r = tid >> 4, n = tid & 15;
    ((float*)&sB[r][0])[n] = bssm[(row0 + r) * 16 + n]; }
  __syncthreads();

  float rowsum[16];
  #pragma unroll
  for (int r = 0; r < 16; r++) rowsum[r] = 0.f;

  #pragma unroll 1
  for (int m = 0; m < 4; m++) {
    const int d0 = m * 512 + tid * 2;
    float4 w[2][4]; float bias[2];
    #pragma unroll
    for (int j = 0; j < 2; j++) {
      const float4* wp = (const float4*)(dtw + (size_t)(d0 + j) * 16);
      w[j][0] = wp[0]; w[j][1] = wp[1]; w[j][2] = wp[2]; w[j][3] = wp[3];
      bias[j] = dtb[d0 + j];
    }
    #pragma unroll
    for (int r = 0; r < 16; r++) {
      float4 b0 = sB[r][0], b1 = sB[r][1], b2 = sB[r][2], b3 = sB[r][3];
      float s = 0.f;
      #pragma unroll
      for (int j = 0; j < 2; j++) {
        float dot = bias[j]
          + b0.x * w[j][0].x + b0.y * w[j][0].y + b0.z * w[j][0].z + b0.w * w[j][0].w
          + b1.x * w[j][1].x + b1.y * w[j][1].y + b1.z * w[j][1].z + b1.w * w[j][1].w
          + b2.x * w[j][2].x + b2.y * w[j][2].y + b2.z * w[j][2].z + b2.w * w[j][2].w
          + b3.x * w[j][3].x + b3.y * w[j][3].y + b3.z * w[j][3].z + b3.w * w[j][3].w;
        s += (dot > 15.f) ? dot : __logf(1.f + __expf(dot));
      }
      rowsum[r] += s;
    }
  }
  #pragma unroll
  for (int r = 0; r < 16; r++)
    #pragma unroll
    for (int off = 32; off > 0; off >>= 1) rowsum[r] += __shfl_xor(rowsum[r], off);
  __shared__ float red[4][16];
  if ((tid & 63) == 0) {
    #pragma unroll
    for (int r = 0; r < 16; r++) red[tid >> 6][r] = rowsum[r];
  }
  __syncthreads();
  if (tid < 16) {
    float mean = (red[0][tid] + red[1][tid] + red[2][tid] + red[3][tid]) * (1.f / DINNER);
    alpha[row0 + tid] = 1.f / (1.f + __expf(-mean));
  }
}

// ---------------- scan pass 1: per-chunk scan from h=0 -> carry ----------------
// grid (b, c) = 4*64 = 256 blocks; 256 thr, thread = d-octet (bf16x8 loads).
__global__ __launch_bounds__(256) void k_scan1(const u16* __restrict__ xc,
    const float* __restrict__ alpha, float* __restrict__ carry) {
  const int c = blockIdx.x & 63;
  const int b = blockIdx.x >> 6;
  const int d0 = threadIdx.x * 8;
  __shared__ float sa[CHUNK];
  if (threadIdx.x < CHUNK) sa[threadIdx.x] = alpha[b * TLEN + c * CHUNK + threadIdx.x];
  __syncthreads();
  const u16* xp = xc + ((size_t)(b * TLEN + c * CHUNK)) * DINNER + d0;
  float h[8];
  #pragma unroll
  for (int j = 0; j < 8; j++) h[j] = 0.f;
  #pragma unroll 4
  for (int i = 0; i < CHUNK; i++) {
    bf16x8 v = *(const bf16x8*)(xp + (size_t)i * DINNER);
    float a = sa[i];
    #pragma unroll
    for (int j = 0; j < 8; j++) h[j] = a * h[j] + (1.f - a) * bf2f(((u16*)&v)[j]);
  }
  float* cp = carry + ((size_t)(b * NCH + c)) * DINNER + d0;
  #pragma unroll
  for (int j = 0; j < 8; j++) cp[j] = h[j];
}

// ---------------- scan pass 2: chunkprod + serial carry combine (in place) -----
__global__ __launch_bounds__(256) void k_scan2(float* __restrict__ carry,
    const float* __restrict__ alpha) {
  int i = blockIdx.x * 256 + threadIdx.x;   // 0..8191 = (b, d); b uniform per block
  int b = i >> 11;
  int d = i & (DINNER - 1);
  __shared__ float sP[NCH];
  if (threadIdx.x < NCH) {
    const float* ap = alpha + b * TLEN + threadIdx.x * CHUNK;
    float p = 1.f;
    for (int j = 0; j < CHUNK; j++) p *= ap[j];
    sP[threadIdx.x] = p;
  }
  __syncthreads();
  float* base = carry + (size_t)b * NCH * DINNER + d;
  float cv[NCH];
  #pragma unroll
  for (int c = 0; c < NCH; c++) cv[c] = base[(size_t)c * DINNER];
  float h = 0.f;
  #pragma unroll
  for (int c = 0; c < NCH; c++) {
    base[(size_t)c * DINNER] = h;       // chunk-entry state Hs
    h = sP[c] * h + cv[c];
  }
}

// ---------------- scan pass 3: re-scan + fused y = (h*D + xc)*silu(z) ----------
// grid (b, c) = 256 blocks; 256 thr, thread = d-octet.
__global__ __launch_bounds__(256) void k_scan3(const u16* __restrict__ xc,
    const u16* __restrict__ xz, const float* __restrict__ alpha,
    const float* __restrict__ Hs, const float* __restrict__ Dp,
    u16* __restrict__ yg) {
  const int c = blockIdx.x & 63;
  const int b = blockIdx.x >> 6;
  const int d0 = threadIdx.x * 8;
  __shared__ float sa[CHUNK];
  if (threadIdx.x < CHUNK) sa[threadIdx.x] = alpha[b * TLEN + c * CHUNK + threadIdx.x];
  __syncthreads();
  float h[8], Dv[8];
  { const float* hp = Hs + ((size_t)(b * NCH + c)) * DINNER + d0;
    #pragma unroll
    for (int j = 0; j < 8; j++) { h[j] = hp[j]; Dv[j] = Dp[d0 + j]; } }
  const size_t row0 = (size_t)(b * TLEN + c * CHUNK);
  #pragma unroll 2
  for (int i = 0; i < CHUNK; i++) {
    const size_t row = row0 + i;
    bf16x8 xv8 = *(const bf16x8*)(xc + row * DINNER + d0);
    bf16x8 zv8 = *(const bf16x8*)(xz + row * 4096 + DINNER + d0);
    const float a = sa[i];
    union { u16 o[8]; int4 v4; } out;
    #pragma unroll
    for (int j = 0; j < 8; j++) {
      float xv = bf2f(((u16*)&xv8)[j]);
      float zv = bf2f(((u16*)&zv8)[j]);
      h[j] = a * h[j] + (1.f - a) * xv;
      float y = h[j] * Dv[j] + xv;
      out.o[j] = f2bf(y * silu_f(zv));
    }
    *(int4*)(yg + row * DINNER + d0) = out.v4;
  }
}

// ---------------- launch --------------------------------------------------------
extern "C" void kernel_launch(void* const* d_in, const int* in_sizes, int n_in,
                              void* d_out, int out_size, void* d_ws, size_t ws_size,
                              hipStream_t stream) {
  const float* x   = (const float*)d_in[0];
  const float* w1  = (const float*)d_in[1];
  const float* cw  = (const float*)d_in[2];
  const float* cb  = (const float*)d_in[3];
  const float* xpw = (const float*)d_in[4];
  const float* dtw = (const float*)d_in[5];
  const float* dtb = (const float*)d_in[6];
  const float* Dp  = (const float*)d_in[7];
  const float* w3  = (const float*)d_in[8];
  float* out = (float*)d_out;
  char* ws = (char*)d_ws;

  u16*   xb    = (u16*)(ws + 0);            // 16.78 MB (dead after gemm1)
  u16*   w1b   = (u16*)(ws + 16777216);     //  8.39 MB
  u16*   w3b   = (u16*)(ws + 25165824);     //  4.19 MB
  u16*   xz    = (u16*)(ws + 29360128);     // 67.11 MB  [8192][4096] bf16
  u16*   xc    = (u16*)(ws + 96468992);     // 33.55 MB  [8192][2048] bf16
  u16*   yg    = (u16*)(ws + 130023424);    // 33.55 MB  [8192][2048] bf16
  float* bssm  = (float*)(ws + 163577856);  // 0.52 MB   [8192][16]
  float* alpha = (float*)(ws + 164102144);  // 32 KB     [8192]
  float* carry = (float*)(ws + 0);          // 2 MB [256][2048] — reuses dead xb
  u16*   xpwb  = (u16*)(ws + 164659456);    // 64 KB     [16][2048] bf16

  k_convert<<<14368, 256, 0, stream>>>(x, w1, w3, xpw, xb, w1b, w3b, xpwb);
  k_gemm8p<4096, 1024, true><<<512, 512, 131072, stream>>>(xb, w1b, xz);
  k_conv   <<<1024, 256, 0, stream>>>(xz, cw, cb, xc);
  k_bssm   <<<256, 256, 0, stream>>>(xc, xpwb, bssm);
  k_alpha  <<<512, 256, 0, stream>>>(bssm, dtw, dtb, alpha);
  k_scan1  <<<256, 256, 0, stream>>>(xc, alpha, carry);
  k_scan2  <<<32, 256, 0, stream>>>(carry, alpha);
  k_scan3  <<<256, 256, 0, stream>>>(xc, xz, alpha, carry, Dp, yg);
  k_gemm2<1024, 2048><<<dim3(16, 64), 256, 0, stream>>>(yg, w3b, out);
}

// Round 8
// 315.129 us; speedup vs baseline: 1.2040x; 1.0759x over previous
//
#include <hip/hip_runtime.h>
#include <stdint.h>

#define TLEN   2048
#define DMODEL 1024
#define DINNER 2048
#define MROWS  8192   // B*T
#define NCH    64
#define CHUNK  32

typedef unsigned short u16;
typedef __bf16 bf16x8 __attribute__((ext_vector_type(8)));
typedef float  f32x4  __attribute__((ext_vector_type(4)));

__device__ __forceinline__ float bf2f(u16 u) {
  union { unsigned int i; float f; } v; v.i = ((unsigned int)u) << 16; return v.f;
}
__device__ __forceinline__ u16 f2bf(float f) {
  union { float f; unsigned int u; } v; v.f = f;
  unsigned int u = v.u;
  return (u16)((u + 0x7fffu + ((u >> 16) & 1u)) >> 16);
}
__device__ __forceinline__ float silu_f(float x) { return x / (1.f + __expf(-x)); }

__device__ __forceinline__ void async16(const u16* g, u16* l) {
  __builtin_amdgcn_global_load_lds(
      (const __attribute__((address_space(1))) void*)(g),
      (__attribute__((address_space(3))) void*)(l),
      16, 0, 0);
}

#define BAR      asm volatile("s_barrier" ::: "memory")
#define WAITV(n) asm volatile("s_waitcnt vmcnt(" #n ")" ::: "memory")
#define PRIO1    __builtin_amdgcn_s_setprio(1)
#define PRIO0    __builtin_amdgcn_s_setprio(0)

// ---------------- fp32 -> bf16 conversion: x, in_proj_w, out_proj_w, xpw -------
__global__ __launch_bounds__(256) void k_convert(const float* __restrict__ x,
    const float* __restrict__ w1, const float* __restrict__ w3,
    const float* __restrict__ xpw,
    u16* __restrict__ xb, u16* __restrict__ w1b, u16* __restrict__ w3b,
    u16* __restrict__ xpwb) {
  int i = blockIdx.x * 256 + threadIdx.x;           // one float4 per thread
  const int nx  = MROWS * DMODEL / 4;               // 2097152
  const int nw1 = 2 * DINNER * DMODEL / 4;          // 1048576
  const int nw3 = DMODEL * DINNER / 4;              //  524288
  const float* src; u16* dst; int j;
  if (i < nx)                  { src = x;   dst = xb;   j = i; }
  else if (i < nx + nw1)       { src = w1;  dst = w1b;  j = i - nx; }
  else if (i < nx + nw1 + nw3) { src = w3;  dst = w3b;  j = i - nx - nw1; }
  else                         { src = xpw; dst = xpwb; j = i - nx - nw1 - nw3; }
  float4 v = ((const float4*)src)[j];
  ushort4 o;
  o.x = f2bf(v.x); o.y = f2bf(v.y); o.z = f2bf(v.z); o.w = f2bf(v.w);
  ((ushort4*)dst)[j] = o;
}

// ================= 256x256 8-phase bf16 GEMM (round-2 schedule, 72 us) =========
__device__ __forceinline__ u16* regp(u16* lds, int s, int mat, int h) {
  return lds + (((s * 2 + mat) * 2 + h) * 8192);
}

__device__ __forceinline__ void read_a(bf16x8 (&dst)[4][2], const u16* reg,
                                       int qa, int fr, int c0, int c1) {
  #pragma unroll
  for (int m = 0; m < 4; m++) {
    const u16* p = reg + (qa * 64 + m * 16 + fr) * 64;
    dst[m][0] = *(const bf16x8*)(p + c0);
    dst[m][1] = *(const bf16x8*)(p + c1);
  }
}
__device__ __forceinline__ void read_b(bf16x8 (&dst)[2][2], const u16* reg,
                                       int rb, int c0, int c1) {
  #pragma unroll
  for (int n = 0; n < 2; n++) {
    const u16* p = reg + (rb + n * 16) * 64;
    dst[n][0] = *(const bf16x8*)(p + c0);
    dst[n][1] = *(const bf16x8*)(p + c1);
  }
}
__device__ __forceinline__ void mfma_quad(f32x4 (&acc)[8][4],
    const bf16x8 (&af)[4][2], const bf16x8 (&bf)[2][2], int qa, int qb) {
  #pragma unroll
  for (int m = 0; m < 4; m++)
    #pragma unroll
    for (int n = 0; n < 2; n++)
      #pragma unroll
      for (int ks = 0; ks < 2; ks++)
        acc[qa * 4 + m][qb * 2 + n] = __builtin_amdgcn_mfma_f32_16x16x32_bf16(
            af[m][ks], bf[n][ks], acc[qa * 4 + m][qb * 2 + n], 0, 0, 0);
}

template<int N, int K, bool OUT_BF16>
__global__ __launch_bounds__(512) void k_gemm8p(const u16* __restrict__ A,
    const u16* __restrict__ Bm, void* __restrict__ C) {
  static_assert(K % 128 == 0, "K must be multiple of 128");
  extern __shared__ u16 lds[];
  const int tid  = threadIdx.x;
  const int lane = tid & 63;
  const int wave = tid >> 6;
  const int wm   = wave >> 2;
  const int wn   = wave & 3;
  const int fr   = lane & 15;
  const int q    = lane >> 4;

  int wg = blockIdx.x, nwg = gridDim.x, swz = wg;
  if ((nwg & 7) == 0) swz = (wg & 7) * (nwg >> 3) + (wg >> 3);
  const int NT_N = N / 256;
  const size_t blockM = (size_t)(swz / NT_N) * 256;
  const size_t blockN = (size_t)(swz % NT_N) * 256;

  const int rsub   = tid >> 3;
  const int srcCol = 8 * ((tid & 7) ^ (rsub & 7));
  const u16* gA = A  + (blockM + rsub) * (size_t)K + srcCol;
  const u16* gB = Bm + (blockN + rsub) * (size_t)K + srcCol;

#define STAGE(sl, mat, h, kt) do {                                           \
    const u16* _g = ((mat) ? gB : gA) + (size_t)(h) * (128 * (size_t)K)      \
                    + (size_t)(kt) * 64;                                     \
    u16* _l = regp(lds, (sl), (mat), (h)) + tid * 8;                         \
    async16(_g, _l);                                                         \
    async16(_g + (size_t)64 * K, _l + 4096);                                 \
  } while (0)

  const int c0 = (((q * 16)      ^ ((fr & 7) << 4)) >> 1);
  const int c1 = (((64 + q * 16) ^ ((fr & 7) << 4)) >> 1);
  const int rb = (wn & 1) * 64 + fr;

  f32x4 acc[8][4] = {};
  bf16x8 a0[4][2], a1[4][2], bl[2][2], bh[2][2];

  const int NT = K / 64;
  const int NITER = K / 128;

  STAGE(0, 0, 0, 0); STAGE(0, 0, 1, 0); STAGE(0, 1, 0, 0); STAGE(0, 1, 1, 0);
  STAGE(1, 1, 0, 1); STAGE(1, 1, 1, 1); STAGE(1, 0, 0, 1);
  WAITV(6);
  BAR;

  for (int it = 0; it < NITER; ++it) {
    const int t2 = 2 * it + 2, t3 = 2 * it + 3;
    const bool pf = (t2 < NT);
    // ---- P1
    read_a(a0, regp(lds, 0, 0, wm), 0, fr, c0, c1);
    read_b(bl, regp(lds, 0, 1, wn >> 1), rb, c0, c1);
    STAGE(1, 0, 1, 2 * it + 1);
    BAR;
    PRIO1; mfma_quad(acc, a0, bl, 0, 0); PRIO0;
    BAR;
    // ---- P2
    read_b(bh, regp(lds, 0, 1, wn >> 1), rb + 32, c0, c1);
    if (pf) STAGE(0, 1, 0, t2);
    BAR;
    PRIO1; mfma_quad(acc, a0, bh, 0, 1); PRIO0;
    BAR;
    // ---- P3
    read_a(a1, regp(lds, 0, 0, wm), 1, fr, c0, c1);
    if (pf) STAGE(0, 1, 1, t2);
    BAR;
    PRIO1; mfma_quad(acc, a1, bl, 1, 0); PRIO0;
    BAR;
    // ---- P4
    if (pf) STAGE(0, 0, 0, t2);
    BAR;
    PRIO1; mfma_quad(acc, a1, bh, 1, 1); PRIO0;
    if (pf) { WAITV(6); } else { WAITV(0); }
    BAR;
    // ---- P5
    read_a(a0, regp(lds, 1, 0, wm), 0, fr, c0, c1);
    read_b(bl, regp(lds, 1, 1, wn >> 1), rb, c0, c1);
    if (pf) STAGE(0, 0, 1, t2);
    BAR;
    PRIO1; mfma_quad(acc, a0, bl, 0, 0); PRIO0;
    BAR;
    // ---- P6
    read_b(bh, regp(lds, 1, 1, wn >> 1), rb + 32, c0, c1);
    if (pf) STAGE(1, 1, 0, t3);
    BAR;
    PRIO1; mfma_quad(acc, a0, bh, 0, 1); PRIO0;
    BAR;
    // ---- P7
    read_a(a1, regp(lds, 1, 0, wm), 1, fr, c0, c1);
    if (pf) STAGE(1, 1, 1, t3);
    BAR;
    PRIO1; mfma_quad(acc, a1, bl, 1, 0); PRIO0;
    BAR;
    // ---- P8
    if (pf) STAGE(1, 0, 0, t3);
    BAR;
    PRIO1; mfma_quad(acc, a1, bh, 1, 1); PRIO0;
    if (pf) { WAITV(6); BAR; } else { BAR; }
  }
#undef STAGE

  {
    const size_t r0  = blockM + (size_t)wm * 128;
    const size_t cc0 = blockN + (size_t)wn * 64;
    #pragma unroll
    for (int m = 0; m < 8; m++)
      #pragma unroll
      for (int n = 0; n < 4; n++)
        #pragma unroll
        for (int r = 0; r < 4; r++) {
          size_t row = r0 + m * 16 + q * 4 + r;
          size_t col = cc0 + n * 16 + fr;
          float v = acc[m][n][r];
          if (OUT_BF16) ((u16*)C)[row * N + col] = f2bf(v);
          else          ((float*)C)[row * N + col] = v;
        }
  }
}

// ---------------- bf16 MFMA GEMM, 128^2 tile (proven baseline; out_proj) ------
template<int N, int K, bool OUT_BF16>
__global__ __launch_bounds__(256) void k_gemm_bt(const u16* __restrict__ A,
    const u16* __restrict__ B, void* __restrict__ C) {
  __shared__ u16 sA[2][128 * 32];       // 16 KB
  __shared__ u16 sB[2][128 * 32];       // 16 KB
  const int tid  = threadIdx.x;
  const int lane = tid & 63;
  const int wave = tid >> 6;            // 0..3
  const int wm   = (wave >> 1) * 64;
  const int wn   = (wave & 1) * 64;
  const int fr   = lane & 15;
  const int q    = lane >> 4;
  const size_t blockM = (size_t)blockIdx.y * 128;
  const size_t blockN = (size_t)blockIdx.x * 128;

  const int srow = lane >> 2;
  const int scol = (lane & 3) * 8;
  const u16* gA = A + (blockM + (size_t)wave * 32 + srow) * (size_t)K + scol;
  const u16* gB = B + (blockN + (size_t)wave * 32 + srow) * (size_t)K + scol;
  u16* lA0 = sA[0] + wave * 1024;
  u16* lA1 = sA[1] + wave * 1024;
  u16* lB0 = sB[0] + wave * 1024;
  u16* lB1 = sB[1] + wave * 1024;

  f32x4 acc[4][4] = {};

  for (int kt = 0; kt < K; kt += 64) {
    async16(gA + kt,                        lA0);
    async16(gA + 16 * (size_t)K + kt,       lA0 + 512);
    async16(gA + kt + 32,                   lA1);
    async16(gA + 16 * (size_t)K + kt + 32,  lA1 + 512);
    async16(gB + kt,                        lB0);
    async16(gB + 16 * (size_t)K + kt,       lB0 + 512);
    async16(gB + kt + 32,                   lB1);
    async16(gB + 16 * (size_t)K + kt + 32,  lB1 + 512);
    __syncthreads();

    #pragma unroll
    for (int h = 0; h < 2; h++) {
      bf16x8 af[4], bfr[4];
      #pragma unroll
      for (int tm = 0; tm < 4; tm++)
        af[tm] = *(const bf16x8*)(sA[h] + (wm + tm * 16 + fr) * 32 + q * 8);
      #pragma unroll
      for (int tn = 0; tn < 4; tn++)
        bfr[tn] = *(const bf16x8*)(sB[h] + (wn + tn * 16 + fr) * 32 + q * 8);
      #pragma unroll
      for (int tm = 0; tm < 4; tm++)
        #pragma unroll
        for (int tn = 0; tn < 4; tn++)
          acc[tm][tn] = __builtin_amdgcn_mfma_f32_16x16x32_bf16(
              af[tm], bfr[tn], acc[tm][tn], 0, 0, 0);
    }
    __syncthreads();
  }

  #pragma unroll
  for (int tm = 0; tm < 4; tm++)
    #pragma unroll
    for (int tn = 0; tn < 4; tn++)
      #pragma unroll
      for (int r = 0; r < 4; r++) {
        size_t row = blockM + wm + tm * 16 + q * 4 + r;
        size_t col = blockN + wn + tn * 16 + fr;
        float v = acc[tm][tn][r];
        if (OUT_BF16) ((u16*)C)[row * N + col] = f2bf(v);
        else          ((float*)C)[row * N + col] = v;
      }
}

// ---------------- depthwise causal conv + SiLU: 8 d x 8 t per thread -----------
__global__ __launch_bounds__(256) void k_conv(const u16* __restrict__ xz,
    const float* __restrict__ cw, const float* __restrict__ cb,
    u16* __restrict__ xc) {
  const int tb = blockIdx.x & 255;
  const int b  = blockIdx.x >> 8;
  const int d0 = threadIdx.x * 8;

  float wgt[8][4], bias[8];
  #pragma unroll
  for (int j = 0; j < 8; j++) {
    float4 wv = ((const float4*)cw)[d0 + j];
    wgt[j][0] = wv.x; wgt[j][1] = wv.y; wgt[j][2] = wv.z; wgt[j][3] = wv.w;
    bias[j] = cb[d0 + j];
  }

  const int t0 = tb * 8;
  const u16* base = xz + ((size_t)(b * TLEN + t0)) * 4096 + d0;
  float win[3][8];
  #pragma unroll
  for (int k = 0; k < 3; k++) {
    const int t = t0 - 3 + k;
    if (t >= 0) {
      bf16x8 v = *(const bf16x8*)(base + (ptrdiff_t)(k - 3) * 4096);
      #pragma unroll
      for (int j = 0; j < 8; j++) win[k][j] = bf2f(((u16*)&v)[j]);
    } else {
      #pragma unroll
      for (int j = 0; j < 8; j++) win[k][j] = 0.f;
    }
  }

  u16* outp = xc + ((size_t)(b * TLEN + t0)) * DINNER + d0;
  #pragma unroll
  for (int i = 0; i < 8; i++) {
    bf16x8 v = *(const bf16x8*)(base + (ptrdiff_t)i * 4096);
    float cur[8];
    #pragma unroll
    for (int j = 0; j < 8; j++) cur[j] = bf2f(((u16*)&v)[j]);
    union { u16 a[8]; int4 v4; } o;
    #pragma unroll
    for (int j = 0; j < 8; j++) {
      float acc = bias[j] + wgt[j][0] * win[0][j] + wgt[j][1] * win[1][j]
                + wgt[j][2] * win[2][j] + wgt[j][3] * cur[j];
      o.a[j] = f2bf(silu_f(acc));
    }
    *(int4*)(outp + (size_t)i * DINNER) = o.v4;
    #pragma unroll
    for (int j = 0; j < 8; j++) { win[0][j] = win[1][j]; win[1][j] = win[2][j]; win[2][j] = cur[j]; }
  }
}

// ---------------- B_ssm: 16 rows/block, 512 blocks = 2/CU ----------------------
__global__ __launch_bounds__(256) void k_bssm(const u16* __restrict__ xc,
    const u16* __restrict__ xpwb, float* __restrict__ bssm) {
  const int tid  = threadIdx.x;
  const int lane = tid & 63;
  const int wave = tid >> 6;            // splits K
  const int fr   = lane & 15;
  const int q    = lane >> 4;
  const size_t row0 = (size_t)blockIdx.x * 16;
  const int k0 = wave * 512;

  f32x4 acc = {};
  #pragma unroll
  for (int kk = 0; kk < 512; kk += 32) {
    const int kb = k0 + kk + q * 8;
    bf16x8 bfrag = *(const bf16x8*)(xpwb + (size_t)fr * DINNER + kb);
    bf16x8 afrag = *(const bf16x8*)(xc + (row0 + fr) * (size_t)DINNER + kb);
    acc = __builtin_amdgcn_mfma_f32_16x16x32_bf16(afrag, bfrag, acc, 0, 0, 0);
  }

  __shared__ float red[4][16][16];      // 4 KB
  #pragma unroll
  for (int r = 0; r < 4; r++)
    red[wave][q * 4 + r][fr] = acc[r];
  __syncthreads();
  { int r = tid >> 4, n = tid & 15;     // 256 threads = 16x16 outputs
    bssm[(row0 + r) * 16 + n] =
        red[0][r][n] + red[1][r][n] + red[2][r][n] + red[3][r][n]; }
}

// ---------------- alpha: 16 rows/block, 2 d-cols/thread/pass, 4 passes ---------
__global__ __launch_bounds__(256) void k_alpha(const float* __restrict__ bssm,
    const float* __restrict__ dtw, const float* __restrict__ dtb,
    float* __restrict__ alpha) {
  const int tid = threadIdx.x;
  const size_t row0 = (size_t)blockIdx.x * 16;
  __shared__ float4 sB[16][4];
  { int r = tid >> 4, n = tid & 15;
    ((float*)&sB[r][0])[n] = bssm[(row0 + r) * 16 + n]; }
  __syncthreads();

  float rowsum[16];
  #pragma unroll
  for (int r = 0; r < 16; r++) rowsum[r] = 0.f;

  #pragma unroll 1
  for (int m = 0; m < 4; m++) {
    const int d0 = m * 512 + tid * 2;
    float4 w[2][4]; float bias[2];
    #pragma unroll
    for (int j = 0; j < 2; j++) {
      const float4* wp = (const float4*)(dtw + (size_t)(d0 + j) * 16);
      w[j][0] = wp[0]; w[j][1] = wp[1]; w[j][2] = wp[2]; w[j][3] = wp[3];
      bias[j] = dtb[d0 + j];
    }
    #pragma unroll
    for (int r = 0; r < 16; r++) {
      float4 b0 = sB[r][0], b1 = sB[r][1], b2 = sB[r][2], b3 = sB[r][3];
      float s = 0.f;
      #pragma unroll
      for (int j = 0; j < 2; j++) {
        float dot = bias[j]
          + b0.x * w[j][0].x + b0.y * w[j][0].y + b0.z * w[j][0].z + b0.w * w[j][0].w
          + b1.x * w[j][1].x + b1.y * w[j][1].y + b1.z * w[j][1].z + b1.w * w[j][1].w
          + b2.x * w[j][2].x + b2.y * w[j][2].y + b2.z * w[j][2].z + b2.w * w[j][2].w
          + b3.x * w[j][3].x + b3.y * w[j][3].y + b3.z * w[j][3].z + b3.w * w[j][3].w;
        s += (dot > 15.f) ? dot : __logf(1.f + __expf(dot));
      }
      rowsum[r] += s;
    }
  }
  #pragma unroll
  for (int r = 0; r < 16; r++)
    #pragma unroll
    for (int off = 32; off > 0; off >>= 1) rowsum[r] += __shfl_xor(rowsum[r], off);
  __shared__ float red[4][16];
  if ((tid & 63) == 0) {
    #pragma unroll
    for (int r = 0; r < 16; r++) red[tid >> 6][r] = rowsum[r];
  }
  __syncthreads();
  if (tid < 16) {
    float mean = (red[0][tid] + red[1][tid] + red[2][tid] + red[3][tid]) * (1.f / DINNER);
    alpha[row0 + tid] = 1.f / (1.f + __expf(-mean));
  }
}

// ---------------- scan pass 1: 4 d/thread, 512 blocks = 2/CU -------------------
// grid: g=blk&1 (d half), c=(blk>>1)&63, b=blk>>7.
__global__ __launch_bounds__(256) void k_scan1(const u16* __restrict__ xc,
    const float* __restrict__ alpha, float* __restrict__ carry) {
  const int g = blockIdx.x & 1;
  const int c = (blockIdx.x >> 1) & 63;
  const int b = blockIdx.x >> 7;
  const int d0 = g * 1024 + threadIdx.x * 4;
  __shared__ float sa[CHUNK];
  if (threadIdx.x < CHUNK) sa[threadIdx.x] = alpha[b * TLEN + c * CHUNK + threadIdx.x];
  __syncthreads();
  const u16* xp = xc + ((size_t)(b * TLEN + c * CHUNK)) * DINNER + d0;
  float h[4];
  #pragma unroll
  for (int j = 0; j < 4; j++) h[j] = 0.f;
  #pragma unroll 4
  for (int i = 0; i < CHUNK; i++) {
    ushort4 v = *(const ushort4*)(xp + (size_t)i * DINNER);
    const u16* vp = (const u16*)&v;
    float a = sa[i];
    #pragma unroll
    for (int j = 0; j < 4; j++) h[j] = a * h[j] + (1.f - a) * bf2f(vp[j]);
  }
  float* cp = carry + ((size_t)(b * NCH + c)) * DINNER + d0;
  *(float4*)cp = *(float4*)h;
}

// ---------------- scan pass 2: chunkprod + carry combine (cv in registers) -----
__global__ __launch_bounds__(256) void k_scan2(float* __restrict__ carry,
    const float* __restrict__ alpha) {
  int i = blockIdx.x * 256 + threadIdx.x;   // 0..8191 = (b, d); b uniform per block
  int b = i >> 11;
  int d = i & (DINNER - 1);
  __shared__ float sP[NCH];
  if (threadIdx.x < NCH) {
    const float* ap = alpha + b * TLEN + threadIdx.x * CHUNK;
    float p = 1.f;
    for (int j = 0; j < CHUNK; j++) p *= ap[j];
    sP[threadIdx.x] = p;
  }
  __syncthreads();
  float* base = carry + (size_t)b * NCH * DINNER + d;
  float cv[NCH];
  #pragma unroll
  for (int c = 0; c < NCH; c++) cv[c] = base[(size_t)c * DINNER];
  float h = 0.f;
  #pragma unroll
  for (int c = 0; c < NCH; c++) {
    base[(size_t)c * DINNER] = h;       // chunk-entry state Hs
    h = sP[c] * h + cv[c];
  }
}

// ---------------- scan pass 3: 4 d/thread, 512 blocks; fused gate --------------
__global__ __launch_bounds__(256) void k_scan3(const u16* __restrict__ xc,
    const u16* __restrict__ xz, const float* __restrict__ alpha,
    const float* __restrict__ Hs, const float* __restrict__ Dp,
    u16* __restrict__ yg) {
  const int g = blockIdx.x & 1;
  const int c = (blockIdx.x >> 1) & 63;
  const int b = blockIdx.x >> 7;
  const int d0 = g * 1024 + threadIdx.x * 4;
  __shared__ float sa[CHUNK];
  if (threadIdx.x < CHUNK) sa[threadIdx.x] = alpha[b * TLEN + c * CHUNK + threadIdx.x];
  __syncthreads();
  float h[4], Dv[4];
  { const float* hp = Hs + ((size_t)(b * NCH + c)) * DINNER + d0;
    #pragma unroll
    for (int j = 0; j < 4; j++) { h[j] = hp[j]; Dv[j] = Dp[d0 + j]; } }
  const size_t row0 = (size_t)(b * TLEN + c * CHUNK);
  #pragma unroll 2
  for (int i = 0; i < CHUNK; i++) {
    const size_t row = row0 + i;
    ushort4 xv4 = *(const ushort4*)(xc + row * DINNER + d0);
    ushort4 zv4 = *(const ushort4*)(xz + row * 4096 + DINNER + d0);
    const float a = sa[i];
    union { u16 o[4]; uint2 v2; } out;
    const u16* xv = (const u16*)&xv4;
    const u16* zv = (const u16*)&zv4;
    #pragma unroll
    for (int j = 0; j < 4; j++) {
      float x = bf2f(xv[j]);
      float z = bf2f(zv[j]);
      h[j] = a * h[j] + (1.f - a) * x;
      float y = h[j] * Dv[j] + x;
      out.o[j] = f2bf(y * silu_f(z));
    }
    *(uint2*)(yg + row * DINNER + d0) = out.v2;
  }
}

// ---------------- launch --------------------------------------------------------
extern "C" void kernel_launch(void* const* d_in, const int* in_sizes, int n_in,
                              void* d_out, int out_size, void* d_ws, size_t ws_size,
                              hipStream_t stream) {
  const float* x   = (const float*)d_in[0];
  const float* w1  = (const float*)d_in[1];
  const float* cw  = (const float*)d_in[2];
  const float* cb  = (const float*)d_in[3];
  const float* xpw = (const float*)d_in[4];
  const float* dtw = (const float*)d_in[5];
  const float* dtb = (const float*)d_in[6];
  const float* Dp  = (const float*)d_in[7];
  const float* w3  = (const float*)d_in[8];
  float* out = (float*)d_out;
  char* ws = (char*)d_ws;

  u16*   xb    = (u16*)(ws + 0);            // 16.78 MB (dead after gemm1)
  u16*   w1b   = (u16*)(ws + 16777216);     //  8.39 MB
  u16*   w3b   = (u16*)(ws + 25165824);     //  4.19 MB
  u16*   xz    = (u16*)(ws + 29360128);     // 67.11 MB  [8192][4096] bf16
  u16*   xc    = (u16*)(ws + 96468992);     // 33.55 MB  [8192][2048] bf16
  u16*   yg    = (u16*)(ws + 130023424);    // 33.55 MB  [8192][2048] bf16
  float* bssm  = (float*)(ws + 163577856);  // 0.52 MB   [8192][16]
  float* alpha = (float*)(ws + 164102144);  // 32 KB     [8192]
  float* carry = (float*)(ws + 0);          // 2 MB [256][2048] — reuses dead xb
  u16*   xpwb  = (u16*)(ws + 164659456);    // 64 KB     [16][2048] bf16

  k_convert<<<14368, 256, 0, stream>>>(x, w1, w3, xpw, xb, w1b, w3b, xpwb);
  k_gemm8p<4096, 1024, true><<<512, 512, 131072, stream>>>(xb, w1b, xz);
  k_conv   <<<1024, 256, 0, stream>>>(xz, cw, cb, xc);
  k_bssm   <<<512, 256, 0, stream>>>(xc, xpwb, bssm);
  k_alpha  <<<512, 256, 0, stream>>>(bssm, dtw, dtb, alpha);
  k_scan1  <<<512, 256, 0, stream>>>(xc, alpha, carry);
  k_scan2  <<<32, 256, 0, stream>>>(carry, alpha);
  k_scan3  <<<512, 256, 0, stream>>>(xc, xz, alpha, carry, Dp, yg);
  k_gemm_bt<1024, 2048, false><<<dim3(8, 64), 256, 0, stream>>>(yg, w3b, out);
}